// Round 5
// baseline (1263.843 us; speedup 1.0000x reference)
//
#include <hip/hip_runtime.h>

// Shapes (fixed for this problem)
#define D_DIM 1024
#define S_DIM 2048
#define B_DIM 4
#define M_DIM 4096
#define NTOK  8192   // B*S
#define OUTN  ((long)NTOK * D_DIM)

typedef unsigned short u16;
typedef __attribute__((ext_vector_type(8))) short short8;  // 8 bf16 (guide-verified frag type)
typedef __attribute__((ext_vector_type(4))) float fx4;

static __device__ __forceinline__ float b2f(u16 u) {
  union { unsigned int i; float f; } v; v.i = ((unsigned int)u) << 16; return v.f;
}
static __device__ __forceinline__ u16 f2b(float f) {
  union { float f; unsigned int i; } v; v.f = f;
  unsigned int r = v.i + 0x7fffu + ((v.i >> 16) & 1u); // RNE
  return (u16)(r >> 16);
}

// ---------------- canary: prefill fp32 output with 1.0 ----------------
// Overwritten by the final GEMM when the pipeline works; if the bench fails
// with absmax ~1.0 we know kernels execute (logic bug); if absmax stays
// 3.857e-2 kernels never ran (infra).
__global__ void canary_kernel(float* __restrict__ out) {
  const long i = ((long)blockIdx.x * 256 + threadIdx.x) * 4;
  float4 v = {1.0f, 1.0f, 1.0f, 1.0f};
  *(float4*)(out + i) = v;
}

// ---------------- embedding gather + positional encoding (fp32 in, bf16 out) ----------------
__global__ void Transformer_33792802685820_kernel(
    const int* __restrict__ x, const float* __restrict__ emb,
    const float* __restrict__ pe, u16* __restrict__ h) {
  const int t = blockIdx.x;          // token index 0..NTOK-1
  const int s = t & (S_DIM - 1);     // position within sequence
  const int row = x[t];
  const int d = threadIdx.x * 4;     // 256 threads * 4 = 1024 = D
  float4 e = *(const float4*)(emb + (long)row * D_DIM + d);
  float4 p = *(const float4*)(pe + (long)s * D_DIM + d);
  ushort4 o;
  o.x = f2b(e.x + p.x);
  o.y = f2b(e.y + p.y);
  o.z = f2b(e.z + p.z);
  o.w = f2b(e.w + p.w);
  *(ushort4*)(h + (long)t * D_DIM + d) = o;
}

// ---------------- transpose fp32 -> bf16: out[C][R] = in[R][C] ----------------
__global__ void transpose_f_kernel(
    const float* __restrict__ in, u16* __restrict__ out, int R, int C) {
  __shared__ float tile[32][33];
  const int c0 = blockIdx.x * 32, r0 = blockIdx.y * 32;
  const int tx = threadIdx.x, ty = threadIdx.y; // 32 x 8
  for (int i = ty; i < 32; i += 8)
    tile[i][tx] = in[(long)(r0 + i) * C + (c0 + tx)];
  __syncthreads();
  for (int i = ty; i < 32; i += 8)
    out[(long)(c0 + i) * R + (r0 + tx)] = f2b(tile[tx][i]);
}

// ---------------- transpose bf16 -> bf16, batched over z ----------------
__global__ void transpose_b_kernel(
    const u16* __restrict__ in, u16* __restrict__ out, int R, int C) {
  __shared__ u16 tile[32][33];
  const long zoff = (long)blockIdx.z * R * C;
  const int c0 = blockIdx.x * 32, r0 = blockIdx.y * 32;
  const int tx = threadIdx.x, ty = threadIdx.y; // 32 x 8
  for (int i = ty; i < 32; i += 8)
    tile[i][tx] = in[zoff + (long)(r0 + i) * C + (c0 + tx)];
  __syncthreads();
  for (int i = ty; i < 32; i += 8)
    out[zoff + (long)(c0 + i) * R + (r0 + tx)] = tile[tx][i];
}

// ---------------- MFMA GEMM: C = act(scale*A@Bt^T + bias) ----------------
// A [M,K] bf16 row-major, Bt [N,K] bf16 row-major. fp32 accumulate via
// 16x16x32 bf16 MFMA, 128x128 tile, BK=32, register-staged two-barrier loop.
// bias fp32. Output bf16 (C) or fp32 (Cf) per OUTF32.
template<bool RELU, bool BIAS, bool OUTF32>
__global__ void gemm_bt(
    const u16* __restrict__ A, const u16* __restrict__ Bt,
    const float* __restrict__ bias, u16* __restrict__ C, float* __restrict__ Cf,
    int M, int N, int K, float scale, long sA, long sB, long sC) {
  __shared__ u16 As[128 * 32];
  __shared__ u16 Bs[128 * 32];
  const int tid  = threadIdx.x;
  const int wave = tid >> 6;
  const int lane = tid & 63;
  const int quad = lane >> 4;
  const int l16  = lane & 15;
  const int wm = (wave & 1) << 6;   // wave row quadrant (0/64)
  const int wn = (wave >> 1) << 6;  // wave col quadrant (0/64)
  A  += (long)blockIdx.z * sA;
  Bt += (long)blockIdx.z * sB;
  const int m0 = blockIdx.y << 7;
  const int n0 = blockIdx.x << 7;

  // thread tid stages 16B chunks: tile rows tid>>2 and (tid>>2)+64, k-offset (tid&3)*8
  const int row_a = tid >> 2;        // 0..63
  const int c4    = (tid & 3) << 3;  // 0,8,16,24
  const u16* gA = A  + (long)(m0 + row_a) * K + c4;
  const u16* gB = Bt + (long)(n0 + row_a) * K + c4;
  uint4* lA = (uint4*)&As[tid * 8];  // row-major [128][32], == row_a*32 + c4
  uint4* lB = (uint4*)&Bs[tid * 8];

  fx4 acc[4][4] = {};

  for (int k0 = 0; k0 < K; k0 += 32) {
    uint4 ra0 = *(const uint4*)(gA + k0);
    uint4 ra1 = *(const uint4*)(gA + (long)64 * K + k0);
    uint4 rb0 = *(const uint4*)(gB + k0);
    uint4 rb1 = *(const uint4*)(gB + (long)64 * K + k0);
    __syncthreads();                 // previous iteration's LDS reads done
    lA[0]   = ra0;
    lA[256] = ra1;                   // +64 rows = 64*32 u16 = 256 uint4
    lB[0]   = rb0;
    lB[256] = rb1;
    __syncthreads();                 // stores visible
    short8 af[4], bfv[4];
    #pragma unroll
    for (int i = 0; i < 4; ++i) {
      af[i]  = *(const short8*)&As[(wm + i * 16 + l16) * 32 + quad * 8];
      bfv[i] = *(const short8*)&Bs[(wn + i * 16 + l16) * 32 + quad * 8];
    }
    #pragma unroll
    for (int mi = 0; mi < 4; ++mi)
      #pragma unroll
      for (int ni = 0; ni < 4; ++ni)
        acc[mi][ni] = __builtin_amdgcn_mfma_f32_16x16x32_bf16(
            af[mi], bfv[ni], acc[mi][ni], 0, 0, 0);
  }

  // epilogue: C/D layout col=lane&15, row=quad*4+reg (verified m89/m91)
  float bv[4];
  #pragma unroll
  for (int ni = 0; ni < 4; ++ni)
    bv[ni] = BIAS ? bias[n0 + wn + ni * 16 + l16] : 0.0f;

  #pragma unroll
  for (int mi = 0; mi < 4; ++mi) {
    #pragma unroll
    for (int r = 0; r < 4; ++r) {
      const long row = m0 + wm + mi * 16 + quad * 4 + r;
      const long base = row * N + n0 + wn + l16;
      #pragma unroll
      for (int ni = 0; ni < 4; ++ni) {
        float v = acc[mi][ni][r] * scale + bv[ni];
        if (RELU) { if (v < 0.0f) v = 0.0f; }  // NaN-transparent ReLU
        if (OUTF32) Cf[(long)blockIdx.z * sC + base + ni * 16] = v;
        else        C [(long)blockIdx.z * sC + base + ni * 16] = f2b(v);
      }
    }
  }
}

// ---------------- masked softmax over row (keys k >= q kept; triu mask) ----------------
__global__ void softmax_kernel(u16* __restrict__ P) {
  const int q = blockIdx.x;
  u16* p = P + ((long)blockIdx.y * S_DIM + q) * S_DIM;
  const int tid = threadIdx.x;
  const int wave = tid >> 6, lane = tid & 63;
  __shared__ float red[4];
  float vals[8];
  float mx = -3.0e38f;
  for (int it = 0; it < 8; ++it) {
    int k = tid + it * 256;
    float v = (k >= q) ? b2f(p[k]) : -3.0e38f;
    vals[it] = v;
    mx = fmaxf(mx, v);
  }
  for (int off = 32; off > 0; off >>= 1)
    mx = fmaxf(mx, __shfl_down(mx, off, 64));
  if (lane == 0) red[wave] = mx;
  __syncthreads();
  mx = fmaxf(fmaxf(red[0], red[1]), fmaxf(red[2], red[3]));
  __syncthreads();
  float sum = 0.0f;
  for (int it = 0; it < 8; ++it) {
    int k = tid + it * 256;
    float e = (k >= q) ? __expf(vals[it] - mx) : 0.0f;
    vals[it] = e;
    sum += e;
  }
  for (int off = 32; off > 0; off >>= 1)
    sum += __shfl_down(sum, off, 64);
  if (lane == 0) red[wave] = sum;
  __syncthreads();
  sum = red[0] + red[1] + red[2] + red[3];
  const float inv = 1.0f / sum;
  for (int it = 0; it < 8; ++it) {
    int k = tid + it * 256;
    p[k] = f2b(vals[it] * inv);
  }
}

extern "C" void kernel_launch(void* const* d_in, const int* in_sizes, int n_in,
                              void* d_out, int out_size, void* d_ws, size_t ws_size,
                              hipStream_t stream) {
  (void)in_sizes; (void)n_in; (void)out_size; (void)ws_size;
  const int*   x   = (const int*)d_in[0];
  const float* emb = (const float*)d_in[1];
  const float* pe  = (const float*)d_in[2];
  const float* wq  = (const float*)d_in[3];
  const float* bq  = (const float*)d_in[4];
  const float* wk  = (const float*)d_in[5];
  const float* bk  = (const float*)d_in[6];
  const float* wv  = (const float*)d_in[7];
  const float* bv  = (const float*)d_in[8];
  const float* w1s = (const float*)d_in[9];
  const float* b1s = (const float*)d_in[10];
  const float* w2s = (const float*)d_in[11];
  const float* b2s = (const float*)d_in[12];
  float* out = (float*)d_out;

  // workspace: bf16 internal activations/weights, ~124 MB.
  // aliases: vT <- q (q dead after scores); mb <- kx+v+P (dead after attention)
  u16* ws  = (u16*)d_ws;
  u16* h   = ws;                               // [8192,1024]
  u16* q   = h  + (long)NTOK * D_DIM;
  u16* kx  = q  + (long)NTOK * D_DIM;
  u16* v   = kx + (long)NTOK * D_DIM;
  u16* P   = v  + (long)NTOK * D_DIM;          // [4][2048,2048]
  u16* wqT = P  + (long)B_DIM * S_DIM * S_DIM; // [1024,1024]
  u16* wkT = wqT + (long)D_DIM * D_DIM;
  u16* wvT = wkT + (long)D_DIM * D_DIM;
  u16* w1T = wvT + (long)D_DIM * D_DIM;        // [4096,1024] per-layer
  u16* w2T = w1T + (long)D_DIM * M_DIM;        // [1024,4096] per-layer
  u16* vT  = q;                                // [4][1024,2048] aliases q
  u16* mb  = kx;                               // [8192,4096] aliases kx,v,P exactly

  const dim3 blk256(256);
  const dim3 blkT(32, 8);

  // canary prefill of fp32 output (overwritten by final GEMM on success)
  canary_kernel<<<dim3(NTOK), blk256, 0, stream>>>(out);

  // QKV weight transposes (fp32 -> bf16 Bt layout)
  transpose_f_kernel<<<dim3(32, 32), blkT, 0, stream>>>(wq, wqT, 1024, 1024);
  transpose_f_kernel<<<dim3(32, 32), blkT, 0, stream>>>(wk, wkT, 1024, 1024);
  transpose_f_kernel<<<dim3(32, 32), blkT, 0, stream>>>(wv, wvT, 1024, 1024);

  // h = bf16(emb[x] + pos_enc)
  Transformer_33792802685820_kernel<<<dim3(NTOK), blk256, 0, stream>>>(x, emb, pe, h);

  // q,k,v projections (M=8192, N=1024, K=1024)
  gemm_bt<false, true, false><<<dim3(8, 64, 1), blk256, 0, stream>>>(h, wqT, bq, q,  nullptr, NTOK, D_DIM, D_DIM, 1.0f, 0, 0, 0);
  gemm_bt<false, true, false><<<dim3(8, 64, 1), blk256, 0, stream>>>(h, wkT, bk, kx, nullptr, NTOK, D_DIM, D_DIM, 1.0f, 0, 0, 0);
  gemm_bt<false, true, false><<<dim3(8, 64, 1), blk256, 0, stream>>>(h, wvT, bv, v,  nullptr, NTOK, D_DIM, D_DIM, 1.0f, 0, 0, 0);

  // scores = (Q @ K^T) / sqrt(D); K already [key,d] = Bt layout
  gemm_bt<false, false, false><<<dim3(16, 16, 4), blk256, 0, stream>>>(q, kx, nullptr, P, nullptr,
      S_DIM, S_DIM, D_DIM, 0.03125f, (long)S_DIM * D_DIM, (long)S_DIM * D_DIM, (long)S_DIM * S_DIM);

  // softmax with triu (self+future) mask, in place
  softmax_kernel<<<dim3(S_DIM, B_DIM), blk256, 0, stream>>>(P);

  // V^T per batch (into dead q), then attn_out = relu(P @ V)
  transpose_b_kernel<<<dim3(32, 64, 4), blkT, 0, stream>>>(v, vT, 2048, 1024);
  gemm_bt<true, false, false><<<dim3(8, 16, 4), blk256, 0, stream>>>(P, vT, nullptr, h, nullptr,
      S_DIM, D_DIM, S_DIM, 1.0f, (long)S_DIM * S_DIM, (long)D_DIM * S_DIM, (long)S_DIM * D_DIM);

  // FFN stack; weights transposed per layer (fp32 -> bf16)
  for (int i = 0; i < 4; ++i) {
    transpose_f_kernel<<<dim3(128, 32), blkT, 0, stream>>>(w1s + (long)i * D_DIM * M_DIM, w1T, 1024, 4096);
    transpose_f_kernel<<<dim3(32, 128), blkT, 0, stream>>>(w2s + (long)i * D_DIM * M_DIM, w2T, 4096, 1024);
    gemm_bt<true, true, false><<<dim3(32, 64, 1), blk256, 0, stream>>>(
        h, w1T, b1s + i * M_DIM, mb, nullptr, NTOK, M_DIM, D_DIM, 1.0f, 0, 0, 0);
    if (i == 3)
      gemm_bt<true, true, true><<<dim3(8, 64, 1), blk256, 0, stream>>>(
          mb, w2T, b2s + i * D_DIM, nullptr, out, NTOK, D_DIM, M_DIM, 1.0f, 0, 0, 0);
    else
      gemm_bt<true, true, false><<<dim3(8, 64, 1), blk256, 0, stream>>>(
          mb, w2T, b2s + i * D_DIM, h, nullptr, NTOK, D_DIM, M_DIM, 1.0f, 0, 0, 0);
  }
}

// Round 6
// 1231.410 us; speedup vs baseline: 1.0263x; 1.0263x over previous
//
#include <hip/hip_runtime.h>

// Shapes (fixed for this problem)
#define D_DIM 1024
#define S_DIM 2048
#define B_DIM 4
#define M_DIM 4096
#define NTOK  8192   // B*S

typedef unsigned short u16;
typedef __attribute__((ext_vector_type(8))) short short8;  // 8 bf16 (guide-verified frag type)
typedef __attribute__((ext_vector_type(4))) float fx4;

static __device__ __forceinline__ float b2f(u16 u) {
  union { unsigned int i; float f; } v; v.i = ((unsigned int)u) << 16; return v.f;
}
static __device__ __forceinline__ u16 f2b(float f) {
  union { float f; unsigned int i; } v; v.f = f;
  unsigned int r = v.i + 0x7fffu + ((v.i >> 16) & 1u); // RNE
  return (u16)(r >> 16);
}
// async global->LDS DMA, 16B per lane (m97 ladder step)
static __device__ __forceinline__ void async16(u16* lds, const u16* g) {
  __builtin_amdgcn_global_load_lds(
      (__attribute__((address_space(1))) void*)(u16*)g,
      (__attribute__((address_space(3))) void*)lds, 16, 0, 0);
}

// ---------------- canary: prefill fp32 output with 1.0 (diagnostic) ----------------
__global__ void canary_kernel(float* __restrict__ out) {
  const long i = ((long)blockIdx.x * 256 + threadIdx.x) * 4;
  float4 v = {1.0f, 1.0f, 1.0f, 1.0f};
  *(float4*)(out + i) = v;
}

// ---------------- embedding gather + positional encoding (fp32 in, bf16 out) ----------------
__global__ void Transformer_33792802685820_kernel(
    const int* __restrict__ x, const float* __restrict__ emb,
    const float* __restrict__ pe, u16* __restrict__ h) {
  const int t = blockIdx.x;          // token index 0..NTOK-1
  const int s = t & (S_DIM - 1);     // position within sequence
  const int row = x[t];
  const int d = threadIdx.x * 4;     // 256 threads * 4 = 1024 = D
  float4 e = *(const float4*)(emb + (long)row * D_DIM + d);
  float4 p = *(const float4*)(pe + (long)s * D_DIM + d);
  ushort4 o;
  o.x = f2b(e.x + p.x);
  o.y = f2b(e.y + p.y);
  o.z = f2b(e.z + p.z);
  o.w = f2b(e.w + p.w);
  *(ushort4*)(h + (long)t * D_DIM + d) = o;
}

// ---------------- transpose fp32 -> bf16: out[C][R] = in[R][C] ----------------
__global__ void transpose_f_kernel(
    const float* __restrict__ in, u16* __restrict__ out, int R, int C) {
  __shared__ float tile[32][33];
  const int c0 = blockIdx.x * 32, r0 = blockIdx.y * 32;
  const int tx = threadIdx.x, ty = threadIdx.y; // 32 x 8
  for (int i = ty; i < 32; i += 8)
    tile[i][tx] = in[(long)(r0 + i) * C + (c0 + tx)];
  __syncthreads();
  for (int i = ty; i < 32; i += 8)
    out[(long)(c0 + i) * R + (r0 + tx)] = f2b(tile[tx][i]);
}

// ---------------- transpose bf16 -> bf16, batched over z ----------------
__global__ void transpose_b_kernel(
    const u16* __restrict__ in, u16* __restrict__ out, int R, int C) {
  __shared__ u16 tile[32][33];
  const long zoff = (long)blockIdx.z * R * C;
  const int c0 = blockIdx.x * 32, r0 = blockIdx.y * 32;
  const int tx = threadIdx.x, ty = threadIdx.y; // 32 x 8
  for (int i = ty; i < 32; i += 8)
    tile[i][tx] = in[zoff + (long)(r0 + i) * C + (c0 + tx)];
  __syncthreads();
  for (int i = ty; i < 32; i += 8)
    out[zoff + (long)(c0 + i) * R + (r0 + tx)] = tile[tx][i];
}

// ---------------- MFMA GEMM: C = act(scale*A@Bt^T + bias) ----------------
// A [M,K] bf16 row-major, Bt [N,K] bf16 row-major. fp32 accumulate via
// 16x16x32 bf16 MFMA, 128x128 tile, BK=32, global_load_lds(16B) staging.
// bias fp32. Output bf16 (C) or fp32 (Cf) per OUTF32.
template<bool RELU, bool BIAS, bool OUTF32>
__global__ void gemm_bt(
    const u16* __restrict__ A, const u16* __restrict__ Bt,
    const float* __restrict__ bias, u16* __restrict__ C, float* __restrict__ Cf,
    int M, int N, int K, float scale, long sA, long sB, long sC) {
  __shared__ u16 As[128 * 32];
  __shared__ u16 Bs[128 * 32];
  const int tid  = threadIdx.x;
  const int wave = tid >> 6;
  const int lane = tid & 63;
  const int quad = lane >> 4;
  const int l16  = lane & 15;
  const int wm = (wave & 1) << 6;   // wave row quadrant (0/64)
  const int wn = (wave >> 1) << 6;  // wave col quadrant (0/64)
  A  += (long)blockIdx.z * sA;
  Bt += (long)blockIdx.z * sB;
  const int m0 = blockIdx.y << 7;
  const int n0 = blockIdx.x << 7;

  // thread tid stages 16B chunks: tile rows tid>>2 and (tid>>2)+64, k-offset (tid&3)*8
  // LDS dest = wave-uniform base + lane*16  (m104 constraint satisfied)
  const int row_a = tid >> 2;        // 0..63
  const int c4    = (tid & 3) << 3;  // 0,8,16,24
  const u16* gA = A  + (long)(m0 + row_a) * K + c4;
  const u16* gB = Bt + (long)(n0 + row_a) * K + c4;
  u16* lA = &As[tid * 8];            // row-major [128][32]
  u16* lB = &Bs[tid * 8];

  fx4 acc[4][4] = {};

  for (int k0 = 0; k0 < K; k0 += 32) {
    async16(lA,            gA + k0);
    async16(lA + 64 * 32,  gA + (long)64 * K + k0);
    async16(lB,            gB + k0);
    async16(lB + 64 * 32,  gB + (long)64 * K + k0);
    __syncthreads();                 // vmcnt drain: DMA data visible in LDS
    short8 af[4], bfv[4];
    #pragma unroll
    for (int i = 0; i < 4; ++i) {
      af[i]  = *(const short8*)&As[(wm + i * 16 + l16) * 32 + quad * 8];
      bfv[i] = *(const short8*)&Bs[(wn + i * 16 + l16) * 32 + quad * 8];
    }
    __syncthreads();                 // all ds_reads done; next DMA may overwrite
    #pragma unroll
    for (int mi = 0; mi < 4; ++mi)
      #pragma unroll
      for (int ni = 0; ni < 4; ++ni)
        acc[mi][ni] = __builtin_amdgcn_mfma_f32_16x16x32_bf16(
            af[mi], bfv[ni], acc[mi][ni], 0, 0, 0);
  }

  // epilogue: C/D layout col=lane&15, row=quad*4+reg (verified m89/m91)
  float bv[4];
  #pragma unroll
  for (int ni = 0; ni < 4; ++ni)
    bv[ni] = BIAS ? bias[n0 + wn + ni * 16 + l16] : 0.0f;

  #pragma unroll
  for (int mi = 0; mi < 4; ++mi) {
    #pragma unroll
    for (int r = 0; r < 4; ++r) {
      const long row = m0 + wm + mi * 16 + quad * 4 + r;
      const long base = row * N + n0 + wn + l16;
      #pragma unroll
      for (int ni = 0; ni < 4; ++ni) {
        float v = acc[mi][ni][r] * scale + bv[ni];
        if (RELU) { if (v < 0.0f) v = 0.0f; }  // NaN-transparent ReLU
        if (OUTF32) Cf[(long)blockIdx.z * sC + base + ni * 16] = v;
        else        C [(long)blockIdx.z * sC + base + ni * 16] = f2b(v);
      }
    }
  }
}

// ---------------- masked softmax over row (keys k >= q kept; triu mask) ----------------
__global__ void softmax_kernel(u16* __restrict__ P) {
  const int q = blockIdx.x;
  u16* p = P + ((long)blockIdx.y * S_DIM + q) * S_DIM;
  const int tid = threadIdx.x;
  const int wave = tid >> 6, lane = tid & 63;
  __shared__ float red[4];
  float vals[8];
  float mx = -3.0e38f;
  for (int it = 0; it < 8; ++it) {
    int k = tid + it * 256;
    float v = (k >= q) ? b2f(p[k]) : -3.0e38f;
    vals[it] = v;
    mx = fmaxf(mx, v);
  }
  for (int off = 32; off > 0; off >>= 1)
    mx = fmaxf(mx, __shfl_down(mx, off, 64));
  if (lane == 0) red[wave] = mx;
  __syncthreads();
  mx = fmaxf(fmaxf(red[0], red[1]), fmaxf(red[2], red[3]));
  __syncthreads();
  float sum = 0.0f;
  for (int it = 0; it < 8; ++it) {
    int k = tid + it * 256;
    float e = (k >= q) ? __expf(vals[it] - mx) : 0.0f;
    vals[it] = e;
    sum += e;
  }
  for (int off = 32; off > 0; off >>= 1)
    sum += __shfl_down(sum, off, 64);
  if (lane == 0) red[wave] = sum;
  __syncthreads();
  sum = red[0] + red[1] + red[2] + red[3];
  const float inv = 1.0f / sum;
  for (int it = 0; it < 8; ++it) {
    int k = tid + it * 256;
    p[k] = f2b(vals[it] * inv);
  }
}

extern "C" void kernel_launch(void* const* d_in, const int* in_sizes, int n_in,
                              void* d_out, int out_size, void* d_ws, size_t ws_size,
                              hipStream_t stream) {
  (void)in_sizes; (void)n_in; (void)out_size; (void)ws_size;
  const int*   x   = (const int*)d_in[0];
  const float* emb = (const float*)d_in[1];
  const float* pe  = (const float*)d_in[2];
  const float* wq  = (const float*)d_in[3];
  const float* bq  = (const float*)d_in[4];
  const float* wk  = (const float*)d_in[5];
  const float* bk  = (const float*)d_in[6];
  const float* wv  = (const float*)d_in[7];
  const float* bv  = (const float*)d_in[8];
  const float* w1s = (const float*)d_in[9];
  const float* b1s = (const float*)d_in[10];
  const float* w2s = (const float*)d_in[11];
  const float* b2s = (const float*)d_in[12];
  float* out = (float*)d_out;

  // workspace: bf16 internal activations/weights, ~124 MB.
  // aliases: vT <- q (q dead after scores); mb <- kx+v+P (dead after attention)
  u16* ws  = (u16*)d_ws;
  u16* h   = ws;                               // [8192,1024]
  u16* q   = h  + (long)NTOK * D_DIM;
  u16* kx  = q  + (long)NTOK * D_DIM;
  u16* v   = kx + (long)NTOK * D_DIM;
  u16* P   = v  + (long)NTOK * D_DIM;          // [4][2048,2048]
  u16* wqT = P  + (long)B_DIM * S_DIM * S_DIM; // [1024,1024]
  u16* wkT = wqT + (long)D_DIM * D_DIM;
  u16* wvT = wkT + (long)D_DIM * D_DIM;
  u16* w1T = wvT + (long)D_DIM * D_DIM;        // [4096,1024] per-layer
  u16* w2T = w1T + (long)D_DIM * M_DIM;        // [1024,4096] per-layer
  u16* vT  = q;                                // [4][1024,2048] aliases q
  u16* mb  = kx;                               // [8192,4096] aliases kx,v,P exactly

  const dim3 blk256(256);
  const dim3 blkT(32, 8);

  // canary prefill of fp32 output (overwritten by final GEMM on success)
  canary_kernel<<<dim3(NTOK), blk256, 0, stream>>>(out);

  // QKV weight transposes (fp32 -> bf16 Bt layout)
  transpose_f_kernel<<<dim3(32, 32), blkT, 0, stream>>>(wq, wqT, 1024, 1024);
  transpose_f_kernel<<<dim3(32, 32), blkT, 0, stream>>>(wk, wkT, 1024, 1024);
  transpose_f_kernel<<<dim3(32, 32), blkT, 0, stream>>>(wv, wvT, 1024, 1024);

  // h = bf16(emb[x] + pos_enc)
  Transformer_33792802685820_kernel<<<dim3(NTOK), blk256, 0, stream>>>(x, emb, pe, h);

  // q,k,v projections (M=8192, N=1024, K=1024)
  gemm_bt<false, true, false><<<dim3(8, 64, 1), blk256, 0, stream>>>(h, wqT, bq, q,  nullptr, NTOK, D_DIM, D_DIM, 1.0f, 0, 0, 0);
  gemm_bt<false, true, false><<<dim3(8, 64, 1), blk256, 0, stream>>>(h, wkT, bk, kx, nullptr, NTOK, D_DIM, D_DIM, 1.0f, 0, 0, 0);
  gemm_bt<false, true, false><<<dim3(8, 64, 1), blk256, 0, stream>>>(h, wvT, bv, v,  nullptr, NTOK, D_DIM, D_DIM, 1.0f, 0, 0, 0);

  // scores = (Q @ K^T) / sqrt(D); K already [key,d] = Bt layout
  gemm_bt<false, false, false><<<dim3(16, 16, 4), blk256, 0, stream>>>(q, kx, nullptr, P, nullptr,
      S_DIM, S_DIM, D_DIM, 0.03125f, (long)S_DIM * D_DIM, (long)S_DIM * D_DIM, (long)S_DIM * S_DIM);

  // softmax with triu (self+future) mask, in place
  softmax_kernel<<<dim3(S_DIM, B_DIM), blk256, 0, stream>>>(P);

  // V^T per batch (into dead q), then attn_out = relu(P @ V)
  transpose_b_kernel<<<dim3(32, 64, 4), blkT, 0, stream>>>(v, vT, 2048, 1024);
  gemm_bt<true, false, false><<<dim3(8, 16, 4), blk256, 0, stream>>>(P, vT, nullptr, h, nullptr,
      S_DIM, D_DIM, S_DIM, 1.0f, (long)S_DIM * S_DIM, (long)D_DIM * S_DIM, (long)S_DIM * D_DIM);

  // FFN stack; weights transposed per layer (fp32 -> bf16)
  for (int i = 0; i < 4; ++i) {
    transpose_f_kernel<<<dim3(128, 32), blkT, 0, stream>>>(w1s + (long)i * D_DIM * M_DIM, w1T, 1024, 4096);
    transpose_f_kernel<<<dim3(32, 128), blkT, 0, stream>>>(w2s + (long)i * D_DIM * M_DIM, w2T, 4096, 1024);
    gemm_bt<true, true, false><<<dim3(32, 64, 1), blk256, 0, stream>>>(
        h, w1T, b1s + i * M_DIM, mb, nullptr, NTOK, M_DIM, D_DIM, 1.0f, 0, 0, 0);
    if (i == 3)
      gemm_bt<true, true, true><<<dim3(8, 64, 1), blk256, 0, stream>>>(
          mb, w2T, b2s + i * D_DIM, nullptr, out, NTOK, D_DIM, M_DIM, 1.0f, 0, 0, 0);
    else
      gemm_bt<true, true, false><<<dim3(8, 64, 1), blk256, 0, stream>>>(
          mb, w2T, b2s + i * D_DIM, h, nullptr, NTOK, D_DIM, M_DIM, 1.0f, 0, 0, 0);
  }
}